// Round 2
// baseline (487.715 us; speedup 1.0000x reference)
//
#include <hip/hip_runtime.h>
#include <hip/hip_bf16.h>

#define TPB 256
#define GR 48  // GEMM rows per block

// ---------- graph preprocessing ----------
__global__ __launch_bounds__(TPB) void zero_cnt_k(int* cnt, int n) {
  int i = blockIdx.x * TPB + threadIdx.x;
  if (i < n) cnt[i] = 0;
}

__global__ __launch_bounds__(TPB) void count_k(const int* __restrict__ dst, int* __restrict__ cnt, int e) {
  int i = blockIdx.x * TPB + threadIdx.x;
  if (i < e) atomicAdd(&cnt[dst[i]], 1);
}

// deg = in-degree + 1 (self loop); always > 0
__global__ __launch_bounds__(TPB) void dis_k(const int* __restrict__ cnt, float* __restrict__ dis, int n) {
  int i = blockIdx.x * TPB + threadIdx.x;
  if (i < n) dis[i] = rsqrtf((float)(cnt[i] + 1));
}

__global__ __launch_bounds__(TPB) void scan1_k(const int* __restrict__ cnt, int* __restrict__ bsum, int n) {
  __shared__ int sm[TPB];
  int tid = threadIdx.x;
  int i = blockIdx.x * TPB + tid;
  sm[tid] = (i < n) ? cnt[i] : 0;
  __syncthreads();
  for (int s = TPB / 2; s > 0; s >>= 1) {
    if (tid < s) sm[tid] += sm[tid + s];
    __syncthreads();
  }
  if (tid == 0) bsum[blockIdx.x] = sm[0];
}

__global__ __launch_bounds__(TPB) void scan2_k(int* __restrict__ bsum, int nb) {
  __shared__ int sm[TPB];
  int tid = threadIdx.x;
  int v = (tid < nb) ? bsum[tid] : 0;
  sm[tid] = v;
  __syncthreads();
  for (int d = 1; d < TPB; d <<= 1) {
    int t = (tid >= d) ? sm[tid - d] : 0;
    __syncthreads();
    sm[tid] += t;
    __syncthreads();
  }
  if (tid < nb) bsum[tid] = sm[tid] - v;  // exclusive
}

__global__ __launch_bounds__(TPB) void scan3_k(const int* __restrict__ cnt, const int* __restrict__ bsum,
                                               int* __restrict__ rowptr, int* __restrict__ cursor,
                                               int n, int e) {
  __shared__ int sm[TPB];
  int tid = threadIdx.x;
  int i = blockIdx.x * TPB + tid;
  int v = (i < n) ? cnt[i] : 0;
  sm[tid] = v;
  __syncthreads();
  for (int d = 1; d < TPB; d <<= 1) {
    int t = (tid >= d) ? sm[tid - d] : 0;
    __syncthreads();
    sm[tid] += t;
    __syncthreads();
  }
  int exc = sm[tid] - v + bsum[blockIdx.x];
  if (i < n) { rowptr[i] = exc; cursor[i] = exc; }
  if (i == n - 1) rowptr[n] = exc + v;  // = E
}

__global__ __launch_bounds__(TPB) void fill_k(const int* __restrict__ src, const int* __restrict__ dst,
                                              int* __restrict__ cursor, int* __restrict__ colidx, int e) {
  int i = blockIdx.x * TPB + threadIdx.x;
  if (i < e) {
    int p = atomicAdd(&cursor[dst[i]], 1);
    colidx[p] = src[i];
  }
}

// ---------- t = h @ W (fp32), register-tiled, W staged in two 32KB k-halves ----------
__global__ __launch_bounds__(TPB) void gemm_k(const float* __restrict__ h, const float* __restrict__ W,
                                              float* __restrict__ t, int n) {
  __shared__ __align__(16) float hs[GR * 128];   // 24 KB, granule-swizzled
  __shared__ __align__(16) float wsh[64 * 128];  // 32 KB = half of W (fp32)
  const int tid = threadIdx.x;
  const int r0 = blockIdx.x * GR;
  // stage h tile (48 rows x 128 cols), swizzle granule slot by row to break stride-128 conflicts
  {
    const float4* h4 = (const float4*)h;
    float4* d4 = (float4*)hs;
#pragma unroll
    for (int i = 0; i < 6; i++) {
      int idx = tid + TPB * i;  // 0..1535 (48 rows * 32 granules)
      int r = idx >> 5, g = idx & 31;
      int gr = r0 + r;
      float4 v = make_float4(0.f, 0.f, 0.f, 0.f);
      if (gr < n) v = h4[(size_t)gr * 32 + g];
      d4[(r << 5) + ((g + r) & 31)] = v;
    }
  }
  const int cg = tid & 15;   // 16 col groups of 8
  const int rs = tid >> 4;   // 16 row slots
  const int c0 = cg << 3;
  float acc[3][8];
#pragma unroll
  for (int i = 0; i < 3; i++)
#pragma unroll
    for (int c = 0; c < 8; c++) acc[i][c] = 0.f;

#pragma unroll
  for (int half = 0; half < 2; half++) {
    __syncthreads();  // half0: hs ready-barrier; half1: protect wsh from in-flight reads
    {
      const float4* s4 = (const float4*)(W + (size_t)half * 64 * 128);
      float4* d4 = (float4*)wsh;
#pragma unroll
      for (int i = 0; i < 8; i++) d4[tid + TPB * i] = s4[tid + TPB * i];
    }
    __syncthreads();
    const int kbase = half << 6;
#pragma unroll 4
    for (int k = 0; k < 64; k += 4) {
      const int g = (kbase + k) >> 2;
      float ha[3][4];
#pragma unroll
      for (int i = 0; i < 3; i++) {
        int r = rs + 16 * i;
        float4 v = ((const float4*)hs)[(r << 5) + ((g + r) & 31)];
        ha[i][0] = v.x; ha[i][1] = v.y; ha[i][2] = v.z; ha[i][3] = v.w;
      }
      float wv[4][8];
#pragma unroll
      for (int kk = 0; kk < 4; kk++) {
        const float4* wp = (const float4*)&wsh[((k + kk) << 7) + c0];
        float4 w0 = wp[0], w1 = wp[1];
        wv[kk][0] = w0.x; wv[kk][1] = w0.y; wv[kk][2] = w0.z; wv[kk][3] = w0.w;
        wv[kk][4] = w1.x; wv[kk][5] = w1.y; wv[kk][6] = w1.z; wv[kk][7] = w1.w;
      }
#pragma unroll
      for (int i = 0; i < 3; i++)
#pragma unroll
        for (int kk = 0; kk < 4; kk++)
#pragma unroll
          for (int c = 0; c < 8; c++)
            acc[i][c] = fmaf(ha[i][kk], wv[kk][c], acc[i][c]);
    }
  }
#pragma unroll
  for (int i = 0; i < 3; i++) {
    int gr = r0 + rs + 16 * i;
    if (gr < n) {
      float4* o = (float4*)&t[(size_t)gr * 128 + c0];
      o[0] = make_float4(acc[i][0], acc[i][1], acc[i][2], acc[i][3]);
      o[1] = make_float4(acc[i][4], acc[i][5], acc[i][6], acc[i][7]);
    }
  }
}

// ---------- h = elu(dis[dst]*(sum_src t[src]*dis[src] + t[dst]*dis[dst]) + b) ----------
// one wave per dst row; lane covers cols {lane, lane+64}
__global__ __launch_bounds__(TPB) void agg_k(const float* __restrict__ t, const float* __restrict__ dis,
                                             const int* __restrict__ rowptr, const int* __restrict__ colidx,
                                             const float* __restrict__ bias, float* __restrict__ hout, int n) {
  int wid = (blockIdx.x * TPB + threadIdx.x) >> 6;
  int lane = threadIdx.x & 63;
  if (wid >= n) return;
  int beg = rowptr[wid], end = rowptr[wid + 1];
  float dd = dis[wid];
  float a0 = 0.f, a1 = 0.f;
  int j = beg;
  for (; j + 1 < end; j += 2) {  // 2-deep to overlap gather latency
    int s0 = colidx[j], s1 = colidx[j + 1];
    float w0 = dis[s0], w1 = dis[s1];
    const float* p0 = t + (size_t)s0 * 128;
    const float* p1 = t + (size_t)s1 * 128;
    float x0 = p0[lane], y0 = p0[lane + 64];
    float x1 = p1[lane], y1 = p1[lane + 64];
    a0 = fmaf(x0, w0, a0); a1 = fmaf(y0, w0, a1);
    a0 = fmaf(x1, w1, a0); a1 = fmaf(y1, w1, a1);
  }
  if (j < end) {
    int s = colidx[j];
    float ww = dis[s];
    const float* p = t + (size_t)s * 128;
    a0 = fmaf(p[lane], ww, a0); a1 = fmaf(p[lane + 64], ww, a1);
  }
  const float* ps = t + (size_t)wid * 128;  // self loop
  a0 = fmaf(ps[lane], dd, a0); a1 = fmaf(ps[lane + 64], dd, a1);
  float v0 = fmaf(a0, dd, bias[lane]);
  float v1 = fmaf(a1, dd, bias[lane + 64]);
  v0 = v0 > 0.f ? v0 : expm1f(v0);
  v1 = v1 > 0.f ? v1 : expm1f(v1);
  hout[(size_t)wid * 128 + lane] = v0;
  hout[(size_t)wid * 128 + lane + 64] = v1;
}

// ---------- out[n] = h[n,:] @ Wl + bl ----------
__global__ __launch_bounds__(TPB) void final_k(const float* __restrict__ h, const float* __restrict__ Wl,
                                               const float* __restrict__ bl, float* __restrict__ out,
                                               int n) {
  int wid = (blockIdx.x * TPB + threadIdx.x) >> 6;
  int lane = threadIdx.x & 63;
  if (wid >= n) return;
  float s = h[(size_t)wid * 128 + lane] * Wl[lane] + h[(size_t)wid * 128 + lane + 64] * Wl[lane + 64];
  s += __shfl_down(s, 32);
  s += __shfl_down(s, 16);
  s += __shfl_down(s, 8);
  s += __shfl_down(s, 4);
  s += __shfl_down(s, 2);
  s += __shfl_down(s, 1);
  if (lane == 0) out[wid] = s + bl[0];
}

extern "C" void kernel_launch(void* const* d_in, const int* in_sizes, int n_in,
                              void* d_out, int out_size, void* d_ws, size_t ws_size,
                              hipStream_t stream) {
  const int N = in_sizes[0] / 128;
  const int E = in_sizes[5] / 2;
  const float* x  = (const float*)d_in[0];
  const float* Ws = (const float*)d_in[1];
  const float* bs = (const float*)d_in[2];
  const float* Wl = (const float*)d_in[3];
  const float* bl = (const float*)d_in[4];
  const int* ei   = (const int*)d_in[5];
  const int* srcA = ei;
  const int* dstA = ei + E;
  float* out = (float*)d_out;

  char* w = (char*)d_ws;
  size_t o = 0;
  auto alloc = [&](size_t bytes) -> void* {
    void* p = w + o;
    o += (bytes + 255) & ~(size_t)255;
    return p;
  };
  int*   cnt    = (int*)  alloc((size_t)N * 4);
  float* dis    = (float*)alloc((size_t)N * 4);
  int*   rowptr = (int*)  alloc((size_t)(N + 1) * 4);
  int*   cursor = (int*)  alloc((size_t)N * 4);
  int*   bsum   = (int*)  alloc(1024);
  int*   colidx = (int*)  alloc((size_t)E * 4);
  float* hbuf   = (float*)alloc((size_t)N * 128 * 4);
  float* tbuf   = (float*)alloc((size_t)N * 128 * 4);
  (void)ws_size; (void)n_in; (void)out_size;

  const int nbN = (N + TPB - 1) / TPB;  // 196 <= 256 (scan2 single-block limit)
  const int nbE = (E + TPB - 1) / TPB;
  const int nbW = (N + 3) / 4;          // one wave per node, 4 waves/block

  zero_cnt_k<<<nbN, TPB, 0, stream>>>(cnt, N);
  count_k<<<nbE, TPB, 0, stream>>>(dstA, cnt, E);
  dis_k<<<nbN, TPB, 0, stream>>>(cnt, dis, N);
  scan1_k<<<nbN, TPB, 0, stream>>>(cnt, bsum, N);
  scan2_k<<<1, TPB, 0, stream>>>(bsum, nbN);
  scan3_k<<<nbN, TPB, 0, stream>>>(cnt, bsum, rowptr, cursor, N, E);
  fill_k<<<nbE, TPB, 0, stream>>>(srcA, dstA, cursor, colidx, E);

  const int gemmGrid = (N + GR - 1) / GR;
  for (int l = 0; l < 3; l++) {
    const float* hin = (l == 0) ? x : hbuf;
    gemm_k<<<gemmGrid, TPB, 0, stream>>>(hin, Ws + (size_t)l * 128 * 128, tbuf, N);
    agg_k<<<nbW, TPB, 0, stream>>>(tbuf, dis, rowptr, colidx, bs + (size_t)l * 128, hbuf, N);
  }
  final_k<<<nbW, TPB, 0, stream>>>(hbuf, Wl, bl, out, N);
}

// Round 3
// 410.944 us; speedup vs baseline: 1.1868x; 1.1868x over previous
//
#include <hip/hip_runtime.h>
#include <hip/hip_bf16.h>
#include <hip/hip_fp16.h>

#define TPB 256
#define GR 48  // GEMM rows per block

// ---------- graph preprocessing ----------
__global__ __launch_bounds__(TPB) void zero_cnt_k(int* cnt, int n) {
  int i = blockIdx.x * TPB + threadIdx.x;
  if (i < n) cnt[i] = 0;
}

__global__ __launch_bounds__(TPB) void count_k(const int* __restrict__ dst, int* __restrict__ cnt, int e) {
  int i = blockIdx.x * TPB + threadIdx.x;
  if (i < e) atomicAdd(&cnt[dst[i]], 1);
}

__global__ __launch_bounds__(TPB) void scan1_k(const int* __restrict__ cnt, int* __restrict__ bsum, int n) {
  __shared__ int sm[TPB];
  int tid = threadIdx.x;
  int i = blockIdx.x * TPB + tid;
  sm[tid] = (i < n) ? cnt[i] : 0;
  __syncthreads();
  for (int s = TPB / 2; s > 0; s >>= 1) {
    if (tid < s) sm[tid] += sm[tid + s];
    __syncthreads();
  }
  if (tid == 0) bsum[blockIdx.x] = sm[0];
}

__global__ __launch_bounds__(TPB) void scan2_k(int* __restrict__ bsum, int nb) {
  __shared__ int sm[TPB];
  int tid = threadIdx.x;
  int v = (tid < nb) ? bsum[tid] : 0;
  sm[tid] = v;
  __syncthreads();
  for (int d = 1; d < TPB; d <<= 1) {
    int t = (tid >= d) ? sm[tid - d] : 0;
    __syncthreads();
    sm[tid] += t;
    __syncthreads();
  }
  if (tid < nb) bsum[tid] = sm[tid] - v;  // exclusive
}

// also computes dis = rsqrt(deg) with deg = cnt+1 (self loop)
__global__ __launch_bounds__(TPB) void scan3_k(const int* __restrict__ cnt, const int* __restrict__ bsum,
                                               int* __restrict__ rowptr, int* __restrict__ cursor,
                                               float* __restrict__ dis, int n, int e) {
  __shared__ int sm[TPB];
  int tid = threadIdx.x;
  int i = blockIdx.x * TPB + tid;
  int v = (i < n) ? cnt[i] : 0;
  sm[tid] = v;
  __syncthreads();
  for (int d = 1; d < TPB; d <<= 1) {
    int t = (tid >= d) ? sm[tid - d] : 0;
    __syncthreads();
    sm[tid] += t;
    __syncthreads();
  }
  int exc = sm[tid] - v + bsum[blockIdx.x];
  if (i < n) {
    rowptr[i] = exc;
    cursor[i] = exc;
    dis[i] = rsqrtf((float)(v + 1));
  }
  if (i == n - 1) rowptr[n] = exc + v;  // = E
}

__global__ __launch_bounds__(TPB) void fill_k(const int* __restrict__ src, const int* __restrict__ dst,
                                              int* __restrict__ cursor, int* __restrict__ colidx, int e) {
  int i = blockIdx.x * TPB + threadIdx.x;
  if (i < e) {
    int p = atomicAdd(&cursor[dst[i]], 1);
    colidx[p] = src[i];
  }
}

// ---------- t = h @ W (fp32 in, fp16 out), register-tiled, W staged in two 32KB k-halves ----------
__global__ __launch_bounds__(TPB) void gemm_k(const float* __restrict__ h, const float* __restrict__ W,
                                              __half* __restrict__ t, int n) {
  __shared__ __align__(16) float hs[GR * 128];   // 24 KB, granule-swizzled
  __shared__ __align__(16) float wsh[64 * 128];  // 32 KB = half of W (fp32)
  const int tid = threadIdx.x;
  const int r0 = blockIdx.x * GR;
  // stage h tile (48 rows x 128 cols), swizzle granule slot by row to break stride-128 conflicts
  {
    const float4* h4 = (const float4*)h;
    float4* d4 = (float4*)hs;
#pragma unroll
    for (int i = 0; i < 6; i++) {
      int idx = tid + TPB * i;  // 0..1535 (48 rows * 32 granules)
      int r = idx >> 5, g = idx & 31;
      int gr = r0 + r;
      float4 v = make_float4(0.f, 0.f, 0.f, 0.f);
      if (gr < n) v = h4[(size_t)gr * 32 + g];
      d4[(r << 5) + ((g + r) & 31)] = v;
    }
  }
  const int cg = tid & 15;   // 16 col groups of 8
  const int rs = tid >> 4;   // 16 row slots
  const int c0 = cg << 3;
  float acc[3][8];
#pragma unroll
  for (int i = 0; i < 3; i++)
#pragma unroll
    for (int c = 0; c < 8; c++) acc[i][c] = 0.f;

#pragma unroll
  for (int half = 0; half < 2; half++) {
    __syncthreads();  // half0: hs ready-barrier; half1: protect wsh from in-flight reads
    {
      const float4* s4 = (const float4*)(W + (size_t)half * 64 * 128);
      float4* d4 = (float4*)wsh;
#pragma unroll
      for (int i = 0; i < 8; i++) d4[tid + TPB * i] = s4[tid + TPB * i];
    }
    __syncthreads();
    const int kbase = half << 6;
#pragma unroll 4
    for (int k = 0; k < 64; k += 4) {
      const int g = (kbase + k) >> 2;
      float ha[3][4];
#pragma unroll
      for (int i = 0; i < 3; i++) {
        int r = rs + 16 * i;
        float4 v = ((const float4*)hs)[(r << 5) + ((g + r) & 31)];
        ha[i][0] = v.x; ha[i][1] = v.y; ha[i][2] = v.z; ha[i][3] = v.w;
      }
      float wv[4][8];
#pragma unroll
      for (int kk = 0; kk < 4; kk++) {
        const float4* wp = (const float4*)&wsh[((k + kk) << 7) + c0];
        float4 w0 = wp[0], w1 = wp[1];
        wv[kk][0] = w0.x; wv[kk][1] = w0.y; wv[kk][2] = w0.z; wv[kk][3] = w0.w;
        wv[kk][4] = w1.x; wv[kk][5] = w1.y; wv[kk][6] = w1.z; wv[kk][7] = w1.w;
      }
#pragma unroll
      for (int i = 0; i < 3; i++)
#pragma unroll
        for (int kk = 0; kk < 4; kk++)
#pragma unroll
          for (int c = 0; c < 8; c++)
            acc[i][c] = fmaf(ha[i][kk], wv[kk][c], acc[i][c]);
    }
  }
#pragma unroll
  for (int i = 0; i < 3; i++) {
    int gr = r0 + rs + 16 * i;
    if (gr < n) {
      __half2* o = (__half2*)(t + (size_t)gr * 128 + c0);  // 16B-aligned (c0 mult of 8)
      o[0] = __floats2half2_rn(acc[i][0], acc[i][1]);
      o[1] = __floats2half2_rn(acc[i][2], acc[i][3]);
      o[2] = __floats2half2_rn(acc[i][4], acc[i][5]);
      o[3] = __floats2half2_rn(acc[i][6], acc[i][7]);
    }
  }
}

// ---------- h = elu(dis[dst]*(sum_src t[src]*dis[src] + t[dst]*dis[dst]) + b) ----------
// one wave per dst row; lane covers cols {2*lane, 2*lane+1} via one half2 load (256B/row/wave)
__global__ __launch_bounds__(TPB) void agg_k(const __half* __restrict__ t, const float* __restrict__ dis,
                                             const int* __restrict__ rowptr, const int* __restrict__ colidx,
                                             const float* __restrict__ bias, float* __restrict__ hout, int n) {
  int wid = (blockIdx.x * TPB + threadIdx.x) >> 6;
  int lane = threadIdx.x & 63;
  if (wid >= n) return;
  int beg = rowptr[wid], end = rowptr[wid + 1];
  float dd = dis[wid];
  const __half2* t2 = (const __half2*)t;  // row stride 64 half2
  float a0 = 0.f, a1 = 0.f;
  int j = beg;
  for (; j + 3 < end; j += 4) {  // 4 independent gather chains in flight
    int s0 = colidx[j], s1 = colidx[j + 1], s2 = colidx[j + 2], s3 = colidx[j + 3];
    float w0 = dis[s0], w1 = dis[s1], w2 = dis[s2], w3 = dis[s3];
    __half2 v0 = t2[(size_t)s0 * 64 + lane];
    __half2 v1 = t2[(size_t)s1 * 64 + lane];
    __half2 v2 = t2[(size_t)s2 * 64 + lane];
    __half2 v3 = t2[(size_t)s3 * 64 + lane];
    float2 f0 = __half22float2(v0);
    float2 f1 = __half22float2(v1);
    float2 f2 = __half22float2(v2);
    float2 f3 = __half22float2(v3);
    a0 = fmaf(f0.x, w0, a0); a1 = fmaf(f0.y, w0, a1);
    a0 = fmaf(f1.x, w1, a0); a1 = fmaf(f1.y, w1, a1);
    a0 = fmaf(f2.x, w2, a0); a1 = fmaf(f2.y, w2, a1);
    a0 = fmaf(f3.x, w3, a0); a1 = fmaf(f3.y, w3, a1);
  }
  for (; j < end; j++) {
    int s = colidx[j];
    float ww = dis[s];
    float2 f = __half22float2(t2[(size_t)s * 64 + lane]);
    a0 = fmaf(f.x, ww, a0); a1 = fmaf(f.y, ww, a1);
  }
  {  // self loop
    float2 fs = __half22float2(t2[(size_t)wid * 64 + lane]);
    a0 = fmaf(fs.x, dd, a0); a1 = fmaf(fs.y, dd, a1);
  }
  float2 b = ((const float2*)bias)[lane];
  float v0 = fmaf(a0, dd, b.x);
  float v1 = fmaf(a1, dd, b.y);
  v0 = v0 > 0.f ? v0 : expm1f(v0);
  v1 = v1 > 0.f ? v1 : expm1f(v1);
  ((float2*)hout)[(size_t)wid * 64 + lane] = make_float2(v0, v1);
}

// ---------- out[n] = h[n,:] @ Wl + bl ----------
__global__ __launch_bounds__(TPB) void final_k(const float* __restrict__ h, const float* __restrict__ Wl,
                                               const float* __restrict__ bl, float* __restrict__ out,
                                               int n) {
  int wid = (blockIdx.x * TPB + threadIdx.x) >> 6;
  int lane = threadIdx.x & 63;
  if (wid >= n) return;
  float s = h[(size_t)wid * 128 + lane] * Wl[lane] + h[(size_t)wid * 128 + lane + 64] * Wl[lane + 64];
  s += __shfl_down(s, 32);
  s += __shfl_down(s, 16);
  s += __shfl_down(s, 8);
  s += __shfl_down(s, 4);
  s += __shfl_down(s, 2);
  s += __shfl_down(s, 1);
  if (lane == 0) out[wid] = s + bl[0];
}

extern "C" void kernel_launch(void* const* d_in, const int* in_sizes, int n_in,
                              void* d_out, int out_size, void* d_ws, size_t ws_size,
                              hipStream_t stream) {
  const int N = in_sizes[0] / 128;
  const int E = in_sizes[5] / 2;
  const float* x  = (const float*)d_in[0];
  const float* Ws = (const float*)d_in[1];
  const float* bs = (const float*)d_in[2];
  const float* Wl = (const float*)d_in[3];
  const float* bl = (const float*)d_in[4];
  const int* ei   = (const int*)d_in[5];
  const int* srcA = ei;
  const int* dstA = ei + E;
  float* out = (float*)d_out;

  char* w = (char*)d_ws;
  size_t o = 0;
  auto alloc = [&](size_t bytes) -> void* {
    void* p = w + o;
    o += (bytes + 255) & ~(size_t)255;
    return p;
  };
  int*    cnt    = (int*)   alloc((size_t)N * 4);
  float*  dis    = (float*) alloc((size_t)N * 4);
  int*    rowptr = (int*)   alloc((size_t)(N + 1) * 4);
  int*    cursor = (int*)   alloc((size_t)N * 4);
  int*    bsum   = (int*)   alloc(1024);
  int*    colidx = (int*)   alloc((size_t)E * 4);
  float*  hbuf   = (float*) alloc((size_t)N * 128 * 4);
  __half* tbuf   = (__half*)alloc((size_t)N * 128 * 2);
  (void)ws_size; (void)n_in; (void)out_size;

  const int nbN = (N + TPB - 1) / TPB;  // 196 <= 256 (scan2 single-block limit)
  const int nbE = (E + TPB - 1) / TPB;
  const int nbW = (N + 3) / 4;          // one wave per node, 4 waves/block

  zero_cnt_k<<<nbN, TPB, 0, stream>>>(cnt, N);
  count_k<<<nbE, TPB, 0, stream>>>(dstA, cnt, E);
  scan1_k<<<nbN, TPB, 0, stream>>>(cnt, bsum, N);
  scan2_k<<<1, TPB, 0, stream>>>(bsum, nbN);
  scan3_k<<<nbN, TPB, 0, stream>>>(cnt, bsum, rowptr, cursor, dis, N, E);
  fill_k<<<nbE, TPB, 0, stream>>>(srcA, dstA, cursor, colidx, E);

  const int gemmGrid = (N + GR - 1) / GR;
  for (int l = 0; l < 3; l++) {
    const float* hin = (l == 0) ? x : hbuf;
    gemm_k<<<gemmGrid, TPB, 0, stream>>>(hin, Ws + (size_t)l * 128 * 128, tbuf, N);
    agg_k<<<nbW, TPB, 0, stream>>>(tbuf, dis, rowptr, colidx, bs + (size_t)l * 128, hbuf, N);
  }
  final_k<<<nbW, TPB, 0, stream>>>(hbuf, Wl, bl, out, N);
}

// Round 4
// 320.983 us; speedup vs baseline: 1.5194x; 1.2803x over previous
//
#include <hip/hip_runtime.h>
#include <hip/hip_fp16.h>

#define TPB 256
#define WST 130  // W LDS row stride (halves): 260B -> bank-conflict-free strided b-frag reads

typedef _Float16 half8 __attribute__((ext_vector_type(8)));
typedef _Float16 half2v __attribute__((ext_vector_type(2)));
typedef float floatx4 __attribute__((ext_vector_type(4)));

// ---------- graph preprocessing ----------
// count in-degree AND record each edge's rank within its dst bucket (no 2nd atomic pass needed)
__global__ __launch_bounds__(TPB) void count_k(const int* __restrict__ dst, int* __restrict__ cnt,
                                               ushort* __restrict__ rank, int e) {
  int i = blockIdx.x * TPB + threadIdx.x;
  if (i < e) {
    int r = atomicAdd(&cnt[dst[i]], 1);
    rank[i] = (ushort)r;  // max in-degree ~50 << 65536 for this problem
  }
}

__global__ __launch_bounds__(TPB) void scan1_k(const int* __restrict__ cnt, int* __restrict__ bsum, int n) {
  __shared__ int sm[TPB];
  int tid = threadIdx.x;
  int i = blockIdx.x * TPB + tid;
  sm[tid] = (i < n) ? cnt[i] : 0;
  __syncthreads();
  for (int s = TPB / 2; s > 0; s >>= 1) {
    if (tid < s) sm[tid] += sm[tid + s];
    __syncthreads();
  }
  if (tid == 0) bsum[blockIdx.x] = sm[0];
}

__global__ __launch_bounds__(TPB) void scan2_k(int* __restrict__ bsum, int nb) {
  __shared__ int sm[TPB];
  int tid = threadIdx.x;
  int v = (tid < nb) ? bsum[tid] : 0;
  sm[tid] = v;
  __syncthreads();
  for (int d = 1; d < TPB; d <<= 1) {
    int t = (tid >= d) ? sm[tid - d] : 0;
    __syncthreads();
    sm[tid] += t;
    __syncthreads();
  }
  if (tid < nb) bsum[tid] = sm[tid] - v;  // exclusive
}

// rowptr + dis = rsqrt(deg+1)
__global__ __launch_bounds__(TPB) void scan3_k(const int* __restrict__ cnt, const int* __restrict__ bsum,
                                               int* __restrict__ rowptr, float* __restrict__ dis, int n) {
  __shared__ int sm[TPB];
  int tid = threadIdx.x;
  int i = blockIdx.x * TPB + tid;
  int v = (i < n) ? cnt[i] : 0;
  sm[tid] = v;
  __syncthreads();
  for (int d = 1; d < TPB; d <<= 1) {
    int t = (tid >= d) ? sm[tid - d] : 0;
    __syncthreads();
    sm[tid] += t;
    __syncthreads();
  }
  int exc = sm[tid] - v + bsum[blockIdx.x];
  if (i < n) {
    rowptr[i] = exc;
    dis[i] = rsqrtf((float)(v + 1));
  }
  if (i == n - 1) rowptr[n] = exc + v;  // = E
}

// atomic-free CSR fill using precomputed rank; ushort colidx (half the scatter bytes)
__global__ __launch_bounds__(TPB) void fill_k(const int* __restrict__ src, const int* __restrict__ dst,
                                              const ushort* __restrict__ rank, const int* __restrict__ rowptr,
                                              ushort* __restrict__ colidx, int e) {
  int i = blockIdx.x * TPB + threadIdx.x;
  if (i < e) {
    colidx[rowptr[dst[i]] + (int)rank[i]] = (ushort)src[i];
  }
}

// fp32 x -> fp16
__global__ __launch_bounds__(TPB) void cvt_k(const float4* __restrict__ x, half8* __restrict__ o, int n8) {
  int i = blockIdx.x * TPB + threadIdx.x;
  if (i < n8) {
    float4 a = x[2 * i], b = x[2 * i + 1];
    half8 v = {(_Float16)a.x, (_Float16)a.y, (_Float16)a.z, (_Float16)a.w,
               (_Float16)b.x, (_Float16)b.y, (_Float16)b.z, (_Float16)b.w};
    o[i] = v;
  }
}

// ---------- t = h @ W, fp16 in / fp16 out, fp32 MFMA accumulate ----------
// block = 4 waves, 64 rows x 128 cols. Each wave: 2 n-tiles x 4 row-tiles, 16x16x32 MFMA.
// Verified layouts: A[m=lane&15][k=8*(lane>>4)+j]; B[k=8*(lane>>4)+j][n=lane&15];
// C/D col=lane&15, row=4*(lane>>4)+reg.
__global__ __launch_bounds__(TPB) void gemm_k(const _Float16* __restrict__ h, const float* __restrict__ W,
                                              _Float16* __restrict__ t, int n) {
  __shared__ _Float16 wlds[128 * WST];  // 33280 B
  const int tid = threadIdx.x;
  // stage W (fp32 row-major) -> fp16 LDS [k][n], stride WST
  {
    const float4* W4 = (const float4*)W;
#pragma unroll
    for (int i = 0; i < 16; i++) {
      int idx = tid + TPB * i;  // 0..4095 float4s
      float4 v = W4[idx];
      int k = idx >> 5;          // 32 float4 per 128-col row
      int nn = (idx & 31) << 2;
      half2v* d = (half2v*)&wlds[k * WST + nn];
      d[0] = half2v{(_Float16)v.x, (_Float16)v.y};
      d[1] = half2v{(_Float16)v.z, (_Float16)v.w};
    }
  }
  __syncthreads();
  const int lane = tid & 63;
  const int wv = tid >> 6;     // wave id 0..3 -> n-tiles {2wv, 2wv+1}
  const int m16 = lane & 15;
  const int q = lane >> 4;
  const int r0 = blockIdx.x * 64;
  // preload all B fragments (shared across all row-tiles)
  half8 bfr[2][4];
#pragma unroll
  for (int nt2 = 0; nt2 < 2; nt2++) {
    const int ncol = 16 * (2 * wv + nt2) + m16;
#pragma unroll
    for (int kit = 0; kit < 4; kit++) {
      const int kb = 32 * kit + 8 * q;
#pragma unroll
      for (int j = 0; j < 8; j++) bfr[nt2][kit][j] = wlds[(kb + j) * WST + ncol];
    }
  }
  floatx4 acc[2][4];
#pragma unroll
  for (int a = 0; a < 2; a++)
#pragma unroll
    for (int b = 0; b < 4; b++) acc[a][b] = (floatx4){0.f, 0.f, 0.f, 0.f};

#pragma unroll
  for (int kit = 0; kit < 4; kit++) {
    half8 af[4];
#pragma unroll
    for (int rt = 0; rt < 4; rt++) {
      int row = r0 + 16 * rt + m16;
      half8 a = {0, 0, 0, 0, 0, 0, 0, 0};
      if (row < n) a = *(const half8*)(h + (size_t)row * 128 + 32 * kit + 8 * q);
      af[rt] = a;
    }
#pragma unroll
    for (int rt = 0; rt < 4; rt++)
#pragma unroll
      for (int nt2 = 0; nt2 < 2; nt2++)
        acc[nt2][rt] = __builtin_amdgcn_mfma_f32_16x16x32_f16(af[rt], bfr[nt2][kit], acc[nt2][rt], 0, 0, 0);
  }
  // epilogue: scalar fp16 stores (each inst covers 4 rows x 16 consecutive cols)
#pragma unroll
  for (int rt = 0; rt < 4; rt++) {
#pragma unroll
    for (int reg = 0; reg < 4; reg++) {
      int row = r0 + 16 * rt + 4 * q + reg;
      if (row < n) {
#pragma unroll
        for (int nt2 = 0; nt2 < 2; nt2++) {
          int col = 16 * (2 * wv + nt2) + m16;
          t[(size_t)row * 128 + col] = (_Float16)acc[nt2][rt][reg];
        }
      }
    }
  }
}

// ---------- h = elu(dis[dst]*(sum t[src]*dis[src] + t[dst]*dis[dst]) + b), fp16 out ----------
// one wave per dst row; lane covers cols {2*lane, 2*lane+1}; 8 gather chains in flight
__global__ __launch_bounds__(TPB) void agg_k(const __half2* __restrict__ t2, const float* __restrict__ dis,
                                             const int* __restrict__ rowptr, const ushort* __restrict__ colidx,
                                             const float* __restrict__ bias, _Float16* __restrict__ hout, int n) {
  int wid = (blockIdx.x * TPB + threadIdx.x) >> 6;
  int lane = threadIdx.x & 63;
  if (wid >= n) return;
  int beg = rowptr[wid], end = rowptr[wid + 1];
  float dd = dis[wid];
  float a0 = 0.f, a1 = 0.f;
  int j = beg;
  for (; j + 7 < end; j += 8) {
    int s[8];
#pragma unroll
    for (int u = 0; u < 8; u++) s[u] = colidx[j + u];
    float w[8];
#pragma unroll
    for (int u = 0; u < 8; u++) w[u] = dis[s[u]];
    float2 f[8];
#pragma unroll
    for (int u = 0; u < 8; u++) f[u] = __half22float2(t2[(size_t)s[u] * 64 + lane]);
#pragma unroll
    for (int u = 0; u < 8; u++) { a0 = fmaf(f[u].x, w[u], a0); a1 = fmaf(f[u].y, w[u], a1); }
  }
  for (; j < end; j++) {
    int s = colidx[j];
    float ww = dis[s];
    float2 f = __half22float2(t2[(size_t)s * 64 + lane]);
    a0 = fmaf(f.x, ww, a0); a1 = fmaf(f.y, ww, a1);
  }
  float2 fs = __half22float2(t2[(size_t)wid * 64 + lane]);  // self loop
  a0 = fmaf(fs.x, dd, a0); a1 = fmaf(fs.y, dd, a1);
  float2 b = ((const float2*)bias)[lane];
  float v0 = fmaf(a0, dd, b.x);
  float v1 = fmaf(a1, dd, b.y);
  v0 = v0 > 0.f ? v0 : expm1f(v0);
  v1 = v1 > 0.f ? v1 : expm1f(v1);
  ((half2v*)hout)[(size_t)wid * 64 + lane] = half2v{(_Float16)v0, (_Float16)v1};
}

// ---------- out[n] = h[n,:] @ Wl + bl ----------
__global__ __launch_bounds__(TPB) void final_k(const __half2* __restrict__ h2, const float* __restrict__ Wl,
                                               const float* __restrict__ bl, float* __restrict__ out, int n) {
  int wid = (blockIdx.x * TPB + threadIdx.x) >> 6;
  int lane = threadIdx.x & 63;
  if (wid >= n) return;
  float2 f = __half22float2(h2[(size_t)wid * 64 + lane]);
  float2 wv = ((const float2*)Wl)[lane];
  float s = f.x * wv.x + f.y * wv.y;
  s += __shfl_down(s, 32);
  s += __shfl_down(s, 16);
  s += __shfl_down(s, 8);
  s += __shfl_down(s, 4);
  s += __shfl_down(s, 2);
  s += __shfl_down(s, 1);
  if (lane == 0) out[wid] = s + bl[0];
}

extern "C" void kernel_launch(void* const* d_in, const int* in_sizes, int n_in,
                              void* d_out, int out_size, void* d_ws, size_t ws_size,
                              hipStream_t stream) {
  const int N = in_sizes[0] / 128;
  const int E = in_sizes[5] / 2;
  const float* x  = (const float*)d_in[0];
  const float* Ws = (const float*)d_in[1];
  const float* bs = (const float*)d_in[2];
  const float* Wl = (const float*)d_in[3];
  const float* bl = (const float*)d_in[4];
  const int* ei   = (const int*)d_in[5];
  const int* srcA = ei;
  const int* dstA = ei + E;
  float* out = (float*)d_out;

  char* w = (char*)d_ws;
  size_t o = 0;
  auto alloc = [&](size_t bytes) -> void* {
    void* p = w + o;
    o += (bytes + 255) & ~(size_t)255;
    return p;
  };
  int*       cnt    = (int*)      alloc((size_t)N * 4);
  float*     dis    = (float*)    alloc((size_t)N * 4);
  int*       rowptr = (int*)      alloc((size_t)(N + 1) * 4);
  ushort*    rank   = (ushort*)   alloc((size_t)E * 2);
  int*       bsum   = (int*)      alloc(1024);
  ushort*    colidx = (ushort*)   alloc((size_t)E * 2);
  _Float16*  hbuf   = (_Float16*) alloc((size_t)N * 128 * 2);
  _Float16*  tbuf   = (_Float16*) alloc((size_t)N * 128 * 2);
  _Float16*  x16    = (_Float16*) alloc((size_t)N * 128 * 2);
  (void)ws_size; (void)n_in; (void)out_size;

  const int nbN = (N + TPB - 1) / TPB;  // 196 <= 256 (scan2 single-block limit)
  const int nbE = (E + TPB - 1) / TPB;
  const int nbW = (N + 3) / 4;          // one wave per node, 4 waves/block

  hipMemsetAsync(cnt, 0, (size_t)N * 4, stream);
  count_k<<<nbE, TPB, 0, stream>>>(dstA, cnt, rank, E);
  scan1_k<<<nbN, TPB, 0, stream>>>(cnt, bsum, N);
  scan2_k<<<1, TPB, 0, stream>>>(bsum, nbN);
  scan3_k<<<nbN, TPB, 0, stream>>>(cnt, bsum, rowptr, dis, N);
  fill_k<<<nbE, TPB, 0, stream>>>(srcA, dstA, rank, rowptr, colidx, E);
  cvt_k<<<(N * 16 + TPB - 1) / TPB, TPB, 0, stream>>>((const float4*)x, (half8*)x16, N * 16);

  const int gemmGrid = (N + 63) / 64;
  for (int l = 0; l < 3; l++) {
    const _Float16* hin = (l == 0) ? x16 : hbuf;
    gemm_k<<<gemmGrid, TPB, 0, stream>>>(hin, Ws + (size_t)l * 128 * 128, tbuf, N);
    agg_k<<<nbW, TPB, 0, stream>>>((const __half2*)tbuf, dis, rowptr, colidx, bs + (size_t)l * 128, hbuf, N);
  }
  final_k<<<nbW, TPB, 0, stream>>>((const __half2*)hbuf, Wl, bl, out, N);
}